// Round 4
// baseline (363.045 us; speedup 1.0000x reference)
//
#include <hip/hip_runtime.h>
#include <hip/hip_bf16.h>
#include <stdint.h>

// Problem constants (B=4096, D=2048, K=8, H2=64)
#define NB 4096
#define ND 2048
#define NK 8
#define NH 64

// GEMM tile: 128x128, BK=32, 16x16x32 bf16 MFMA, 256 threads (4 waves, 2x2)
#define BM 128
#define BN 128
#define BK 32
#define MAX_ROWS 5120   // 4096 + 8*128 padding worst case
#define MAX_TILES 40

typedef __bf16 bf16;
typedef __bf16 bf16x8 __attribute__((ext_vector_type(8)));
typedef float floatx4 __attribute__((ext_vector_type(4)));

// Workspace layout (bytes)
#define OFF_KIDX   0u          // 4096 int
#define OFF_ORDER  16384u      // 5120 int (-1 = padding row)
#define OFF_META   40960u      // 81 ints: [0]=n_mt, [1..40]=branch, [41..80]=row0
#define OFF_CUR    41472u      // 8 int cursors
#define OFF_C2S    41536u      // 8 float
#define OFF_XG     65536u      // 5120*2048 bf16 = 20971520 B
#define OFF_WB     21037056u   // 8*2048*2048 bf16 = 67108864 B -> end 88145920

// ---------------------------------------------------------------------------
// Prep stage 1: branch index per sample + order[] = -1 init. 16 blocks.
// ---------------------------------------------------------------------------
__global__ void kidx_kernel(const float* __restrict__ intention,
                            int* __restrict__ kidx,
                            int* __restrict__ order)
{
    const int b = blockIdx.x * 256 + threadIdx.x;   // 0..4095
    float4 a = *(const float4*)(intention + (size_t)b * NK);
    float4 c = *(const float4*)(intention + (size_t)b * NK + 4);
    int k = 0;
    if (a.y > 0.5f) k = 1;
    if (a.z > 0.5f) k = 2;
    if (a.w > 0.5f) k = 3;
    if (c.x > 0.5f) k = 4;
    if (c.y > 0.5f) k = 5;
    if (c.z > 0.5f) k = 6;
    if (c.w > 0.5f) k = 7;
    kidx[b] = k;
    order[b] = -1;
    if (b < MAX_ROWS - NB) order[NB + b] = -1;
}

// ---------------------------------------------------------------------------
// Prep stage 2: single small block. Per-branch counts, M-tile table, branch
// cursors; wave 0 computes c2s[k] = b3 + sum_h relu(W2[h,k]+b2[h])*W3[D+h].
// ---------------------------------------------------------------------------
__global__ void meta_kernel(const int* __restrict__ kidx,
                            const float* __restrict__ W2,
                            const float* __restrict__ b2,
                            const float* __restrict__ W3,
                            const float* __restrict__ b3,
                            int* __restrict__ meta,
                            int* __restrict__ cursors,
                            float* __restrict__ c2s)
{
    __shared__ int cnt[NK];
    const int tid = threadIdx.x;
    if (tid < NK) cnt[tid] = 0;
    __syncthreads();

    for (int i = tid; i < NB; i += 256)
        atomicAdd(&cnt[kidx[i] & 7], 1);

    if (tid < 64) {
        const int k = tid & 7;
        const int hc = tid >> 3;
        float s = 0.f;
#pragma unroll
        for (int j = 0; j < 8; j++) {
            int h = hc * 8 + j;
            float v = W2[h * NK + k] + b2[h];
            if (v > 0.f) s += v * W3[ND + h];
        }
        s += __shfl_xor(s, 8, 64);
        s += __shfl_xor(s, 16, 64);
        s += __shfl_xor(s, 32, 64);
        if (tid < 8) c2s[k] = s + b3[0];
    }
    __syncthreads();

    if (tid == 0) {
        int running = 0, nt = 0;
        for (int k = 0; k < NK; k++) {
            cursors[k] = running;
            int ntile = (cnt[k] + BM - 1) / BM;
            for (int t = 0; t < ntile && nt < MAX_TILES; t++) {
                meta[1 + nt] = k;
                meta[1 + MAX_TILES + nt] = running + t * BM;
                nt++;
            }
            running += ntile * BM;
        }
        meta[0] = nt;
    }
}

// ---------------------------------------------------------------------------
// Prep stage 3: scatter samples into branch-grouped order + out init. 16 blk.
// ---------------------------------------------------------------------------
__global__ void scatter_kernel(const int* __restrict__ kidx,
                               int* __restrict__ cursors,
                               const float* __restrict__ c2s,
                               int* __restrict__ order,
                               float* __restrict__ out)
{
    const int b = blockIdx.x * 256 + threadIdx.x;
    const int k = kidx[b] & 7;
    const int pos = atomicAdd(&cursors[k], 1);
    if (pos >= 0 && pos < MAX_ROWS) order[pos] = b;
    out[b] = c2s[k];
}

// ---------------------------------------------------------------------------
// Gather + convert x rows to bf16 into branch-grouped padded xg.
// ---------------------------------------------------------------------------
__global__ void gather_x_kernel(const float* __restrict__ x,
                                const int* __restrict__ order,
                                bf16* __restrict__ xg)
{
    const int row = blockIdx.x;
    const int t = threadIdx.x;
    const int b = order[row];
    bf16* dst = xg + (size_t)row * ND + t * 8;
    bf16x8 v;
    if (b < 0 || b >= NB) {
#pragma unroll
        for (int i = 0; i < 8; i++) v[i] = (bf16)0.f;
    } else {
        const float* src = x + (size_t)b * ND + t * 8;
        float4 a = *(const float4*)(src);
        float4 c = *(const float4*)(src + 4);
        v[0] = (bf16)a.x; v[1] = (bf16)a.y; v[2] = (bf16)a.z; v[3] = (bf16)a.w;
        v[4] = (bf16)c.x; v[5] = (bf16)c.y; v[6] = (bf16)c.z; v[7] = (bf16)c.w;
    }
    *(bf16x8*)dst = v;
}

// ---------------------------------------------------------------------------
// Convert W1 (row d*8+k) into per-branch contiguous bf16 Wb[k][d][c].
// ---------------------------------------------------------------------------
__global__ void conv_w1_kernel(const float* __restrict__ W1,
                               bf16* __restrict__ Wb)
{
    const int r = blockIdx.x;      // 0..16383
    const int t = threadIdx.x;
    const int d = r >> 3;
    const int k = r & 7;
    const float* src = W1 + (size_t)r * ND + t * 8;
    bf16* dst = Wb + ((size_t)k * ND + d) * ND + t * 8;
    float4 a = *(const float4*)(src);
    float4 c = *(const float4*)(src + 4);
    bf16x8 v;
    v[0] = (bf16)a.x; v[1] = (bf16)a.y; v[2] = (bf16)a.z; v[3] = (bf16)a.w;
    v[4] = (bf16)c.x; v[5] = (bf16)c.y; v[6] = (bf16)c.z; v[7] = (bf16)c.w;
    *(bf16x8*)dst = v;
}

// ---------------------------------------------------------------------------
// GEMM: 256 threads = 4 waves (wm,wn in {0,1}), each wave 64x64 via 4x4
// 16x16x32 MFMA. Fragment-ordered LDS: each buffer is 8 groups of 512 bf16;
// group g holds rows g*16..g*16+15, with lane l's 16B chunk at g*1024B +
// l*16B containing row (l&15), k-chunk (l>>4)*8. ds_read_b128 at
// base + lane*16 is then conflict-free; global_load_lds staging produces it
// with per-lane addresses that still coalesce (16 rows x 64B per wave-op).
// Epilogue: +b1, relu, *W3, 16-lane shuffle reduce, atomicAdd into out.
// ---------------------------------------------------------------------------
__global__ void __launch_bounds__(256)
gemm_kernel(const bf16* __restrict__ xg,
            const bf16* __restrict__ Wb,
            const int* __restrict__ order,
            const int* __restrict__ meta,
            const float* __restrict__ b1,
            const float* __restrict__ W3,
            float* __restrict__ out)
{
    int n_mt = meta[0];
    if (n_mt > MAX_TILES) n_mt = MAX_TILES;
    const int mt = blockIdx.y;
    if (mt >= n_mt) return;
    const int kbr = meta[1 + mt] & 7;
    int row0 = meta[1 + MAX_TILES + mt];
    if (row0 < 0) row0 = 0;
    if (row0 > MAX_ROWS - BM) row0 = MAX_ROWS - BM;
    const int col0 = blockIdx.x * BN;

    __shared__ bf16 As[BM * BK];   // 8 KB, 8 groups x 512
    __shared__ bf16 Bs[BN * BK];   // 8 KB
    __shared__ int rowb[BM];

    const int tid = threadIdx.x;
    const int lane = tid & 63;
    const int wid = tid >> 6;      // 0..3
    const int wm = wid >> 1;       // 0..1
    const int wn = wid & 1;        // 0..1

    if (tid < BM) rowb[tid] = order[row0 + tid];

    // staging: wave `wid` fills groups g = wid*2 + r, r in {0,1}.
    const int fr = lane & 15;      // row within 16-row group
    const int fq = lane >> 4;      // k-quad (8 bf16)
    const bf16* gA0 = xg + (size_t)(row0 + wid * 32 + fr) * ND + fq * 8;
    const bf16* gA1 = gA0 + (size_t)16 * ND;
    const bf16* gB0 = Wb + ((size_t)kbr * ND + col0 + wid * 32 + fr) * ND + fq * 8;
    const bf16* gB1 = gB0 + (size_t)16 * ND;
    bf16* lA0 = As + (wid * 2) * 512;    // wave-uniform LDS bases
    bf16* lA1 = As + (wid * 2 + 1) * 512;
    bf16* lB0 = Bs + (wid * 2) * 512;
    bf16* lB1 = Bs + (wid * 2 + 1) * 512;

    floatx4 zero = {0.f, 0.f, 0.f, 0.f};
    floatx4 acc[4][4];
#pragma unroll
    for (int i = 0; i < 4; i++)
#pragma unroll
        for (int j = 0; j < 4; j++) acc[i][j] = zero;

    for (int kk = 0; kk < ND; kk += BK) {
        __builtin_amdgcn_global_load_lds(
            (const __attribute__((address_space(1))) void*)(gA0 + kk),
            (__attribute__((address_space(3))) void*)lA0, 16, 0, 0);
        __builtin_amdgcn_global_load_lds(
            (const __attribute__((address_space(1))) void*)(gA1 + kk),
            (__attribute__((address_space(3))) void*)lA1, 16, 0, 0);
        __builtin_amdgcn_global_load_lds(
            (const __attribute__((address_space(1))) void*)(gB0 + kk),
            (__attribute__((address_space(3))) void*)lB0, 16, 0, 0);
        __builtin_amdgcn_global_load_lds(
            (const __attribute__((address_space(1))) void*)(gB1 + kk),
            (__attribute__((address_space(3))) void*)lB1, 16, 0, 0);
        __syncthreads();

        bf16x8 af[4], bfv[4];
#pragma unroll
        for (int i = 0; i < 4; i++) {
            af[i]  = *(const bf16x8*)(As + (wm * 4 + i) * 512 + lane * 8);
            bfv[i] = *(const bf16x8*)(Bs + (wn * 4 + i) * 512 + lane * 8);
        }
#pragma unroll
        for (int i = 0; i < 4; i++)
#pragma unroll
            for (int j = 0; j < 4; j++)
                acc[i][j] = __builtin_amdgcn_mfma_f32_16x16x32_bf16(
                    af[i], bfv[j], acc[i][j], 0, 0, 0);
        __syncthreads();
    }

    // Epilogue. C/D layout: col = lane&15, row = (lane>>4)*4 + reg.
    const int colq = lane & 15;
    const int quad = lane >> 4;
    float bias[4], w3v[4];
#pragma unroll
    for (int j = 0; j < 4; j++) {
        int d = col0 + wn * 64 + j * 16 + colq;
        bias[j] = b1[d * NK + kbr];
        w3v[j] = W3[d];
    }
#pragma unroll
    for (int i = 0; i < 4; i++) {
#pragma unroll
        for (int r = 0; r < 4; r++) {
            float s = 0.f;
#pragma unroll
            for (int j = 0; j < 4; j++) {
                float v = acc[i][j][r] + bias[j];
                s += (v > 0.f) ? v * w3v[j] : 0.f;
            }
#pragma unroll
            for (int m = 1; m < 16; m <<= 1) s += __shfl_xor(s, m, 64);
            if (colq == 0) {
                int b = rowb[wm * 64 + i * 16 + quad * 4 + r];
                if (b >= 0 && b < NB) atomicAdd(out + b, s);
            }
        }
    }
}

// ---------------------------------------------------------------------------
extern "C" void kernel_launch(void* const* d_in, const int* in_sizes, int n_in,
                              void* d_out, int out_size, void* d_ws, size_t ws_size,
                              hipStream_t stream)
{
    const float* x         = (const float*)d_in[0];
    const float* intention = (const float*)d_in[1];
    const float* W1        = (const float*)d_in[2];
    const float* b1        = (const float*)d_in[3];
    const float* W2        = (const float*)d_in[4];
    const float* b2        = (const float*)d_in[5];
    const float* W3        = (const float*)d_in[6];
    const float* b3        = (const float*)d_in[7];
    float* out = (float*)d_out;

    char* ws = (char*)d_ws;
    int*   kidx    = (int*)(ws + OFF_KIDX);
    int*   order   = (int*)(ws + OFF_ORDER);
    int*   meta    = (int*)(ws + OFF_META);
    int*   cursors = (int*)(ws + OFF_CUR);
    float* c2s     = (float*)(ws + OFF_C2S);
    bf16*  xg      = (bf16*)(ws + OFF_XG);
    bf16*  Wb      = (bf16*)(ws + OFF_WB);

    kidx_kernel<<<dim3(16), dim3(256), 0, stream>>>(intention, kidx, order);
    meta_kernel<<<dim3(1), dim3(256), 0, stream>>>(
        kidx, W2, b2, W3, b3, meta, cursors, c2s);
    scatter_kernel<<<dim3(16), dim3(256), 0, stream>>>(
        kidx, cursors, c2s, order, out);
    conv_w1_kernel<<<dim3(NK * ND), dim3(256), 0, stream>>>(W1, Wb);
    gather_x_kernel<<<dim3(MAX_ROWS), dim3(256), 0, stream>>>(x, order, xg);
    gemm_kernel<<<dim3(ND / BN, MAX_TILES), dim3(256), 0, stream>>>(
        xg, Wb, order, meta, b1, W3, out);
}

// Round 6
// 312.130 us; speedup vs baseline: 1.1631x; 1.1631x over previous
//
#include <hip/hip_runtime.h>
#include <hip/hip_bf16.h>
#include <stdint.h>

// Problem constants (B=4096, D=2048, K=8, H2=64)
#define NB 4096
#define ND 2048
#define NK 8
#define NH 64

// GEMM tile: 128x128, BK=32, 16x16x32 bf16 MFMA, 256 threads (4 waves, 2x2)
#define BM 128
#define BN 128
#define BK 32
#define MAX_ROWS 5120   // 4096 + 8*127 padding worst case
#define MAX_TILES 40

// fused prep grid partition
#define CONV_BLOCKS  (NK * ND)     // 16384: W1 row -> Wb
#define XCONV_BLOCKS NB            // 4096: x row -> bf16 (original order)
#define KIDX_BLOCKS  (NB / 256)    // 16: kidx + per-block histogram
#define PREP_GRID    (CONV_BLOCKS + XCONV_BLOCKS + KIDX_BLOCKS)

typedef __bf16 bf16;
typedef __bf16 bf16x8 __attribute__((ext_vector_type(8)));
typedef float floatx4 __attribute__((ext_vector_type(4)));

// Workspace layout (bytes)
#define OFF_KIDX   0u          // 4096 int
#define OFF_ORDER  16384u      // 5120 int (padding slots stay poisoned -> negative)
#define OFF_META   40960u      // 81 ints: [0]=n_mt, [1..40]=branch, [41..80]=row0
#define OFF_CUR    41472u      // 8 int cursors
#define OFF_C2S    41536u      // 8 float
#define OFF_CNTP   41600u      // 16*8 int per-block partial counts
#define OFF_XC     65536u      // 4096*2048 bf16 = 16777216 B
#define OFF_WB     16842752u   // 8*2048*2048 bf16 = 67108864 B -> end 83951616

__device__ inline void cvt_row16(const float* __restrict__ src, bf16* __restrict__ dst) {
    float4 a = *(const float4*)(src);
    float4 c = *(const float4*)(src + 4);
    bf16x8 v;
    v[0] = (bf16)a.x; v[1] = (bf16)a.y; v[2] = (bf16)a.z; v[3] = (bf16)a.w;
    v[4] = (bf16)c.x; v[5] = (bf16)c.y; v[6] = (bf16)c.z; v[7] = (bf16)c.w;
    *(bf16x8*)dst = v;
}

// ---------------------------------------------------------------------------
// Dispatch 1 (fused, all order-independent): W1->Wb bf16 branch-split,
// x->xc bf16 (original row order), kidx + per-block branch histograms.
// ---------------------------------------------------------------------------
__global__ void __launch_bounds__(256)
prep_conv_kernel(const float* __restrict__ x,
                 const float* __restrict__ intention,
                 const float* __restrict__ W1,
                 int* __restrict__ kidx,
                 int* __restrict__ cntp,
                 bf16* __restrict__ xc,
                 bf16* __restrict__ Wb)
{
    const int blk = blockIdx.x;
    const int tid = threadIdx.x;

    if (blk < CONV_BLOCKS) {
        // one W1 row (d*8+k) -> Wb[k][d][:]
        const int d = blk >> 3;
        const int k = blk & 7;
        cvt_row16(W1 + (size_t)blk * ND + tid * 8,
                  Wb + ((size_t)k * ND + d) * ND + tid * 8);
    } else if (blk < CONV_BLOCKS + XCONV_BLOCKS) {
        const int row = blk - CONV_BLOCKS;
        cvt_row16(x + (size_t)row * ND + tid * 8,
                  xc + (size_t)row * ND + tid * 8);
    } else {
        __shared__ int h[NK];
        const int hb = blk - CONV_BLOCKS - XCONV_BLOCKS;   // 0..15
        if (tid < NK) h[tid] = 0;
        __syncthreads();
        const int b = hb * 256 + tid;
        float4 a = *(const float4*)(intention + (size_t)b * NK);
        float4 c = *(const float4*)(intention + (size_t)b * NK + 4);
        int k = 0;
        if (a.y > 0.5f) k = 1;
        if (a.z > 0.5f) k = 2;
        if (a.w > 0.5f) k = 3;
        if (c.x > 0.5f) k = 4;
        if (c.y > 0.5f) k = 5;
        if (c.z > 0.5f) k = 6;
        if (c.w > 0.5f) k = 7;
        kidx[b] = k;
        atomicAdd(&h[k], 1);
        __syncthreads();
        if (tid < NK) cntp[hb * NK + tid] = h[tid];
    }
}

// ---------------------------------------------------------------------------
// Dispatch 2: single small block. Sum partial counts, build M-tile table +
// branch base cursors; wave 1 computes c2s[k] = b3 + sum_h relu(W2+b2)*W3.
// ---------------------------------------------------------------------------
__global__ void __launch_bounds__(256)
meta_kernel(const int* __restrict__ cntp,
            const float* __restrict__ W2,
            const float* __restrict__ b2,
            const float* __restrict__ W3,
            const float* __restrict__ b3,
            int* __restrict__ meta,
            int* __restrict__ cursors,
            float* __restrict__ c2s)
{
    __shared__ int cnt[NK];
    const int tid = threadIdx.x;
    if (tid < NK) {
        int s = 0;
#pragma unroll
        for (int i = 0; i < KIDX_BLOCKS; i++) s += cntp[i * NK + tid];
        cnt[tid] = s;
    }
    if (tid >= 64 && tid < 128) {
        const int l = tid - 64;
        const int k = l & 7;
        const int hc = l >> 3;
        float s = 0.f;
#pragma unroll
        for (int j = 0; j < 8; j++) {
            int h = hc * 8 + j;
            float v = W2[h * NK + k] + b2[h];
            if (v > 0.f) s += v * W3[ND + h];
        }
        s += __shfl_xor(s, 8, 64);
        s += __shfl_xor(s, 16, 64);
        s += __shfl_xor(s, 32, 64);
        if (l < 8) c2s[k] = s + b3[0];
    }
    __syncthreads();
    if (tid == 0) {
        int running = 0, nt = 0;
        for (int k = 0; k < NK; k++) {
            cursors[k] = running;
            int ntile = (cnt[k] + BM - 1) / BM;
            for (int t = 0; t < ntile && nt < MAX_TILES; t++) {
                meta[1 + nt] = k;
                meta[1 + MAX_TILES + nt] = running + t * BM;
                nt++;
            }
            running += ntile * BM;
        }
        meta[0] = nt;
    }
}

// ---------------------------------------------------------------------------
// Dispatch 3: wave-aggregated scatter into branch-grouped order + out init.
// Ballot per branch -> one atomicAdd per wave per branch (<=512 total RMWs).
// ---------------------------------------------------------------------------
__global__ void __launch_bounds__(256)
scatter_kernel(const int* __restrict__ kidx,
               int* __restrict__ cursors,
               const float* __restrict__ c2s,
               int* __restrict__ order,
               float* __restrict__ out)
{
    const int b = blockIdx.x * 256 + threadIdx.x;   // 0..4095, all active
    const int lane = threadIdx.x & 63;
    const int k = kidx[b] & 7;
    out[b] = c2s[k];

    const unsigned long long below = (lane == 63) ? ~0ull >> 1
                                   : ((1ull << lane) - 1);
    int pos = 0;
#pragma unroll
    for (int kk = 0; kk < NK; kk++) {
        unsigned long long m = __ballot(k == kk);
        if (m) {
            int leader = __ffsll((long long)m) - 1;
            int base = 0;
            if (lane == leader) base = atomicAdd(&cursors[kk], __popcll(m));
            base = __shfl(base, leader, 64);
            if (k == kk) pos = base + __popcll(m & below);
        }
    }
    if (pos >= 0 && pos < MAX_ROWS) order[pos] = b;
}

// ---------------------------------------------------------------------------
// Dispatch 4: per-branch bf16 GEMM + fused epilogue (R1 body, A row-indexed).
// A-tile staged straight from xc via per-lane row gather (global side of
// global_load_lds is unconstrained; only LDS side must be lane-linear).
// Epilogue: +b1, relu, *W3, 16-lane shuffle reduce, atomicAdd into out.
// ---------------------------------------------------------------------------
__global__ void __launch_bounds__(256)
gemm_kernel(const bf16* __restrict__ xc,
            const bf16* __restrict__ Wb,
            const int* __restrict__ order,
            const int* __restrict__ meta,
            const float* __restrict__ b1,
            const float* __restrict__ W3,
            float* __restrict__ out)
{
    int n_mt = meta[0];
    if (n_mt > MAX_TILES) n_mt = MAX_TILES;
    const int mt = blockIdx.y;
    if (mt >= n_mt) return;
    const int kbr = meta[1 + mt] & 7;
    int row0 = meta[1 + MAX_TILES + mt];
    if (row0 < 0) row0 = 0;
    if (row0 > MAX_ROWS - BM) row0 = MAX_ROWS - BM;
    const int col0 = blockIdx.x * BN;

    __shared__ bf16 As[BM * BK];   // 8 KB row-major, 64B row stride
    __shared__ bf16 Bs[BN * BK];   // 8 KB
    __shared__ int rowb[BM];

    const int tid = threadIdx.x;
    const int lane = tid & 63;
    const int wid = tid >> 6;
    const int wm = wid >> 1;
    const int wn = wid & 1;

    if (tid < BM) {
        int b = order[row0 + tid];
        rowb[tid] = (b >= 0 && b < NB) ? b : -1;
    }
    __syncthreads();

    const int srow = tid >> 2;            // 0..63
    const int scol = (tid & 3) * 8;
    const int ra0 = rowb[srow];
    const int ra1 = rowb[64 + srow];
    const bf16* pa0 = xc + (size_t)(ra0 < 0 ? 0 : ra0) * ND + scol;
    const bf16* pa1 = xc + (size_t)(ra1 < 0 ? 0 : ra1) * ND + scol;
    const bf16* pb0 = Wb + ((size_t)kbr * ND + col0 + srow) * ND + scol;
    const bf16* pb1 = pb0 + (size_t)64 * ND;
    bf16* la0 = As + wid * 512;           // wave-uniform LDS bases (elements)
    bf16* la1 = As + 2048 + wid * 512;
    bf16* lb0 = Bs + wid * 512;
    bf16* lb1 = Bs + 2048 + wid * 512;

    floatx4 zero = {0.f, 0.f, 0.f, 0.f};
    floatx4 acc[4][4];
#pragma unroll
    for (int i = 0; i < 4; i++)
#pragma unroll
        for (int j = 0; j < 4; j++) acc[i][j] = zero;

    const int qk = (lane >> 4) * 8;
    const int mrow = lane & 15;

    for (int kk = 0; kk < ND; kk += BK) {
        __builtin_amdgcn_global_load_lds(
            (const __attribute__((address_space(1))) void*)(pa0 + kk),
            (__attribute__((address_space(3))) void*)la0, 16, 0, 0);
        __builtin_amdgcn_global_load_lds(
            (const __attribute__((address_space(1))) void*)(pa1 + kk),
            (__attribute__((address_space(3))) void*)la1, 16, 0, 0);
        __builtin_amdgcn_global_load_lds(
            (const __attribute__((address_space(1))) void*)(pb0 + kk),
            (__attribute__((address_space(3))) void*)lb0, 16, 0, 0);
        __builtin_amdgcn_global_load_lds(
            (const __attribute__((address_space(1))) void*)(pb1 + kk),
            (__attribute__((address_space(3))) void*)lb1, 16, 0, 0);
        __syncthreads();

        bf16x8 af[4], bfv[4];
#pragma unroll
        for (int i = 0; i < 4; i++) {
            af[i]  = *(const bf16x8*)(As + (wm * 64 + i * 16 + mrow) * BK + qk);
            bfv[i] = *(const bf16x8*)(Bs + (wn * 64 + i * 16 + mrow) * BK + qk);
        }
#pragma unroll
        for (int i = 0; i < 4; i++)
#pragma unroll
            for (int j = 0; j < 4; j++)
                acc[i][j] = __builtin_amdgcn_mfma_f32_16x16x32_bf16(
                    af[i], bfv[j], acc[i][j], 0, 0, 0);
        __syncthreads();
    }

    // Epilogue. C/D layout: col = lane&15, row = (lane>>4)*4 + reg.
    const int colq = lane & 15;
    const int quad = lane >> 4;
    float bias[4], w3v[4];
#pragma unroll
    for (int j = 0; j < 4; j++) {
        int d = col0 + wn * 64 + j * 16 + colq;
        bias[j] = b1[d * NK + kbr];
        w3v[j] = W3[d];
    }
#pragma unroll
    for (int i = 0; i < 4; i++) {
#pragma unroll
        for (int r = 0; r < 4; r++) {
            float s = 0.f;
#pragma unroll
            for (int j = 0; j < 4; j++) {
                float v = acc[i][j][r] + bias[j];
                s += (v > 0.f) ? v * w3v[j] : 0.f;
            }
#pragma unroll
            for (int m = 1; m < 16; m <<= 1) s += __shfl_xor(s, m, 64);
            if (colq == 0) {
                int b = rowb[wm * 64 + i * 16 + quad * 4 + r];
                if (b >= 0) atomicAdd(out + b, s);
            }
        }
    }
}

// ---------------------------------------------------------------------------
extern "C" void kernel_launch(void* const* d_in, const int* in_sizes, int n_in,
                              void* d_out, int out_size, void* d_ws, size_t ws_size,
                              hipStream_t stream)
{
    const float* x         = (const float*)d_in[0];
    const float* intention = (const float*)d_in[1];
    const float* W1        = (const float*)d_in[2];
    const float* b1        = (const float*)d_in[3];
    const float* W2        = (const float*)d_in[4];
    const float* b2        = (const float*)d_in[5];
    const float* W3        = (const float*)d_in[6];
    const float* b3        = (const float*)d_in[7];
    float* out = (float*)d_out;

    char* ws = (char*)d_ws;
    int*   kidx    = (int*)(ws + OFF_KIDX);
    int*   order   = (int*)(ws + OFF_ORDER);
    int*   meta    = (int*)(ws + OFF_META);
    int*   cursors = (int*)(ws + OFF_CUR);
    float* c2s     = (float*)(ws + OFF_C2S);
    int*   cntp    = (int*)(ws + OFF_CNTP);
    bf16*  xc      = (bf16*)(ws + OFF_XC);
    bf16*  Wb      = (bf16*)(ws + OFF_WB);

    prep_conv_kernel<<<dim3(PREP_GRID), dim3(256), 0, stream>>>(
        x, intention, W1, kidx, cntp, xc, Wb);
    meta_kernel<<<dim3(1), dim3(256), 0, stream>>>(
        cntp, W2, b2, W3, b3, meta, cursors, c2s);
    scatter_kernel<<<dim3(NB / 256), dim3(256), 0, stream>>>(
        kidx, cursors, c2s, order, out);
    gemm_kernel<<<dim3(ND / BN, MAX_TILES), dim3(256), 0, stream>>>(
        xc, Wb, order, meta, b1, W3, out);
}